// Round 17
// baseline (357.735 us; speedup 1.0000x reference)
//
#include <hip/hip_runtime.h>
#include <stdint.h>

// FFM: B=4096, F=20 fields x S=500 feats, K=16.
// E2[b, i*336 + g*16 + k] = sum_s x[b,i*500+s]*v[g,i*500+s,k]  (g<20)
// E2[b, i*336 + 320]      = sum_s x[b,i*500+s]*w[i*500+s]      (linear partial)
// out[b] = sum_i E2[b,i,320] + sum_{i<j,k} E2[b,i*336+j*16+k]*E2[b,j*336+i*16+k]
// k2 is FUSED into k1: per batch-tile atomic counter; the 20th (last) field
// block to finish runs the pair reduction for its 64 rows (overlaps other GEMMs).

#define NF 20
#define FS 500
#define TFEAT 10000
#define KD 16
#define NCOL 336        // 21 frags: 320 interaction cols + 16-col w block
#define NFRG 21
#define NB 4096
#define ROWE (NF * NCOL)  // 6720

typedef __bf16 bf16x8 __attribute__((ext_vector_type(8)));
typedef __bf16 bf16x2 __attribute__((ext_vector_type(2)));
typedef float  f32x4  __attribute__((ext_vector_type(4)));
typedef unsigned int u32x4 __attribute__((ext_vector_type(4)));

typedef __attribute__((address_space(1))) const void* as1cv;
typedef __attribute__((address_space(3))) void* as3v;

__device__ inline void gload_lds16(const void* g, void* l) {
  __builtin_amdgcn_global_load_lds((as1cv)g, (as3v)l, 16, 0, 0);
}

// ---------------- prep: VtS in STAGED order (unchanged, verified R9-R16).
// VtS[((i*16+t32)*21+q)*512 + l*8 + e] = B-panel value for row n=16q+(l>>2),
// kk = t32*32 + ((l&3)^((l>>3)&3))*8 + e.  n<320 -> v; n==320 -> w; else 0.
__global__ __launch_bounds__(256) void prep_vt(const float* __restrict__ v,
                                               const float* __restrict__ w,
                                               __bf16* __restrict__ VtS) {
  const int i = blockIdx.x / NFRG;
  const int q = blockIdx.x % NFRG;
  const int tdx = threadIdx.x;
  __shared__ float lv[FS * 17];
  if (q < NF) {  // panel for g=q: lv[s*17+k] = v[g, i*500+s, k]
    const int k = tdx & 15, sb = tdx >> 4;
    const float* vb = v + ((size_t)q * TFEAT + (size_t)i * FS) * KD;
    for (int it = 0; it < 32; ++it) {
      int s = it * 16 + sb;
      if (s < FS) lv[s * 17 + k] = vb[(size_t)s * KD + k];
    }
    __syncthreads();
  }
  const float* wf = w + (size_t)i * FS;
  __bf16* base = VtS + ((size_t)i * 16 * NFRG + q) * 512;
  for (int it = 0; it < 4; ++it) {
    int p = it * 256 + tdx;            // (t32,l) pair: 16*64 = 1024
    int t = p >> 6, l = p & 63;
    int r = l >> 2;                    // row within group (= k for q<20)
    int kk = t * 32 + (((l & 3) ^ ((l >> 3) & 3)) << 3);
    bf16x8 h;
#pragma unroll
    for (int e = 0; e < 8; ++e) {
      int s = kk + e;
      float val = 0.f;
      if (s < FS) {
        if (q < NF) val = lv[s * 17 + r];
        else if (r == 0) val = wf[s];
      }
      h[e] = (__bf16)val;
    }
    *(bf16x8*)(base + (size_t)t * (NFRG * 512) + l * 8) = h;
  }
}

// ---------------- K1: per-field GEMM (R12 body, verified best) + fused finisher.
// BM=64, BN=336, BK=64, 8 K-steps, 4 waves. Single-buffered 2-barrier loop,
// k-halves use verified 0-conflict XOR sub-layouts. A reg-staged distance-1.
// LDS 51.2 KB -> 3 blocks/CU. XCD-bijective swizzle.
__global__ __launch_bounds__(256, 3) void k1_gemm(
    const float* __restrict__ x, const __bf16* __restrict__ VtS,
    __bf16* __restrict__ E2, float* __restrict__ out, int* __restrict__ cnt,
    int chunk_base, int tiles) {
  __shared__ __bf16 As[2][64][32];        // k-halves, 8192 B
  __shared__ __bf16 Bs[2][NCOL * 32];     // k-halves, 43008 B
  __shared__ int lastFlag;

  int bid = blockIdx.x;
  const int nwg = gridDim.x;
  if ((nwg & 7) == 0) {                   // bijective XCD swizzle
    int cpx = nwg >> 3;
    bid = (bid & 7) * cpx + (bid >> 3);
  }
  const int i  = bid / tiles;
  const int tb = bid % tiles;
  const int tid = threadIdx.x;
  const int lane = tid & 63, wid = tid >> 6;
  const int b0 = chunk_base + tb * 64;

  // A stage (per thread): row = tid>>2, 16 f32 cols at (tid&3)*16 within 64-step
  const int arow = tid >> 2;
  const int ac16 = (tid & 3) * 16;
  const int ah  = (tid & 3) >> 1;                  // k-half this thread writes
  const int gh0 = (2 * (tid & 3)) & 3;             // granule-in-half (0 or 2)
  const int rsw = (arow >> 1) & 3;                 // row swizzle
  const float* xrow = x + (size_t)(b0 + arow) * TFEAT + i * FS;
  const __bf16* VtSi = VtS + (size_t)i * 16 * NFRG * 512 + lane * 8;

  auto issueB = [&](int t) {   // stage substeps 2t,2t+1 into halves 0,1
#pragma unroll
    for (int jj = 0; jj < 6; ++jj) {
      int q = wid + 4 * jj;
      if (q < NFRG) {
        gload_lds16(VtSi + ((size_t)(2 * t) * NFRG + q) * 512,
                    (void*)&Bs[0][q * 512]);
        gload_lds16(VtSi + ((size_t)(2 * t + 1) * NFRG + q) * 512,
                    (void*)&Bs[1][q * 512]);
      }
    }
  };

  f32x4 ar_[4];
  auto aload = [&](int t) {
#pragma unroll
    for (int j = 0; j < 4; ++j) {
      int c = t * 64 + ac16 + j * 4;
      if (c > 496) c = 496;              // clamp: junk cols pair with zero B rows
      ar_[j] = *(const f32x4*)(xrow + c);
    }
  };
  auto astore = [&]() {
    bf16x8 h0, h1;
#pragma unroll
    for (int e = 0; e < 4; ++e) {
      h0[e] = (__bf16)ar_[0][e]; h0[4 + e] = (__bf16)ar_[1][e];
      h1[e] = (__bf16)ar_[2][e]; h1[4 + e] = (__bf16)ar_[3][e];
    }
    *(bf16x8*)(&As[ah][arow][((gh0)     ^ rsw) * 8]) = h0;
    *(bf16x8*)(&As[ah][arow][((gh0 + 1) ^ rsw) * 8]) = h1;
  };

  const int nfr = wid ? 5 : 6;
  const int Fbase = wid ? (1 + wid * 5) : 0;
  const int ar = lane & 15, akc = lane >> 4;

  f32x4 acc[4][6];
#pragma unroll
  for (int m = 0; m < 4; ++m)
#pragma unroll
    for (int nf = 0; nf < 6; ++nf) acc[m][nf] = (f32x4){0.f, 0.f, 0.f, 0.f};

  // prologue: tile 0 fully staged
  aload(0);
  issueB(0);
  astore();
  asm volatile("s_waitcnt vmcnt(0) lgkmcnt(0)" ::: "memory");
  __builtin_amdgcn_s_barrier();

  for (int t = 0; t < 8; ++t) {
    if (t < 7) aload(t + 1);             // 4 dwordx4, age under compute
    __builtin_amdgcn_sched_barrier(0);

#pragma unroll
    for (int ks = 0; ks < 2; ++ks) {
      bf16x8 af[4];
#pragma unroll
      for (int m = 0; m < 4; ++m) {
        int row = m * 16 + ar;
        int pch = akc ^ ((row >> 1) & 3);
        af[m] = *(const bf16x8*)(&As[ks][row][pch * 8]);
      }
#pragma unroll
      for (int nf = 0; nf < 6; ++nf)
        if (nf < nfr) {
          int n_ = (Fbase + nf) * 16 + ar;
          int pc = akc ^ ((n_ >> 1) & 3);
          bf16x8 bfr = *(const bf16x8*)&Bs[ks][n_ * 32 + pc * 8];
#pragma unroll
          for (int m = 0; m < 4; ++m)
            acc[m][nf] = __builtin_amdgcn_mfma_f32_16x16x32_bf16(af[m], bfr,
                                                                 acc[m][nf], 0, 0, 0);
        }
    }
    if (t < 7) {
      __builtin_amdgcn_s_barrier();      // all waves done reading LDS tile t
      issueB(t + 1);                     // 12 glds (issued first)
      astore();                          // ds_write; reg-wait leaves glds in flight
      asm volatile("s_waitcnt vmcnt(0) lgkmcnt(0)" ::: "memory");
      __builtin_amdgcn_s_barrier();      // tile t+1 ready
    }
  }

  // epilogue: C/D layout col=lane&15, row=(lane>>4)*4+r
  const int lr4 = akc * 4, lcol = lane & 15;
#pragma unroll
  for (int m = 0; m < 4; ++m)
#pragma unroll
    for (int nf = 0; nf < 6; ++nf)
      if (nf < nfr) {
        int n = (Fbase + nf) * 16 + lcol;
#pragma unroll
        for (int r = 0; r < 4; ++r) {
          int bl = tb * 64 + m * 16 + lr4 + r;
          E2[(size_t)bl * ROWE + i * NCOL + n] = (__bf16)acc[m][nf][r];
        }
      }

  // ---- fused finisher: last of the 20 field-blocks for this batch-tile
  // runs the pair+linear reduction for rows [tb*64, tb*64+64).
  const int tileId = (chunk_base >> 6) + tb;
  __syncthreads();                       // all E2 stores of this block drained
  if (tid == 0) {
    __threadfence();                     // device-scope release (L2 writeback)
    int prev = atomicAdd(cnt + tileId, 1);
    lastFlag = (prev == NF - 1) ? 1 : 0;
    if (lastFlag) __threadfence();       // acquire (invalidate stale lines)
  }
  __syncthreads();
  if (!lastFlag) return;

  // 4 waves x 16 rows; E2 is L2/L3-hot. Direct global reads, k2 math verbatim.
  for (int rr = 0; rr < 16; ++rr) {
    const int blr = wid * 16 + rr;
    const __bf16* er = E2 + (size_t)(tb * 64 + blr) * ROWE;
    const int k = lane & 15, g = lane >> 4;
    float sum = 0.f;
    for (int ii = g; ii < NF; ii += 4)
      for (int j = ii + 1; j < NF; ++j)
        sum += (float)er[ii * NCOL + j * 16 + k] * (float)er[j * NCOL + ii * 16 + k];
    if (lane < NF) sum += (float)er[lane * NCOL + 320];   // linear term
#pragma unroll
    for (int off = 32; off; off >>= 1) sum += __shfl_xor(sum, off);
    if (lane == 0) out[b0 + blr] = sum;
  }
}

extern "C" void kernel_launch(void* const* d_in, const int* in_sizes, int n_in,
                              void* d_out, int out_size, void* d_ws, size_t ws_size,
                              hipStream_t stream) {
  const float* x = (const float*)d_in[0];
  const float* w = (const float*)d_in[1];
  const float* v = (const float*)d_in[2];
  float* out = (float*)d_out;
  char* ws = (char*)d_ws;

  const size_t vt_bytes = (size_t)NF * 16 * NFRG * 512 * 2;   // 6,881,280
  __bf16* VtS = (__bf16*)ws;
  int* cnt = (int*)(ws + vt_bytes);                           // 64 tile counters
  __bf16* E2 = (__bf16*)(ws + vt_bytes + 256);

  size_t eavail = (ws_size > vt_bytes + 256) ? ws_size - vt_bytes - 256 : 0;
  int Bc = NB;
  while (Bc > 64 && (size_t)Bc * ROWE * 2 > eavail) Bc >>= 1;

  hipMemsetAsync(cnt, 0, (NB / 64) * sizeof(int), stream);
  prep_vt<<<NF * NFRG, 256, 0, stream>>>(v, w, VtS);
  for (int cb = 0; cb < NB; cb += Bc) {
    int tiles = Bc / 64;
    k1_gemm<<<NF * tiles, 256, 0, stream>>>(x, VtS, E2, out, cnt, cb, tiles);
  }
}

// Round 18
// 196.934 us; speedup vs baseline: 1.8165x; 1.8165x over previous
//
#include <hip/hip_runtime.h>
#include <stdint.h>

// FFM: B=4096, F=20 fields x S=500 feats, K=16.
// E2[b, i*336 + g*16 + k] = sum_s x[b,i*500+s]*v[g,i*500+s,k]  (g<20)
// E2[b, i*336 + 320]      = sum_s x[b,i*500+s]*w[i*500+s]      (linear partial)
// out[b] = sum_i E2[b,i,320] + sum_{i<j,k} E2[b,i*336+j*16+k]*E2[b,j*336+i*16+k]
// k2 FUSED into k1: per batch-tile atomic counter; the 20th (last) field block
// runs the pair reduction for its 64 rows, with LDS-staged coalesced reads.

#define NF 20
#define FS 500
#define TFEAT 10000
#define KD 16
#define NCOL 336        // 21 frags: 320 interaction cols + 16-col w block
#define NFRG 21
#define NB 4096
#define ROWE (NF * NCOL)  // 6720

typedef __bf16 bf16x8 __attribute__((ext_vector_type(8)));
typedef __bf16 bf16x2 __attribute__((ext_vector_type(2)));
typedef float  f32x4  __attribute__((ext_vector_type(4)));
typedef unsigned int u32x4 __attribute__((ext_vector_type(4)));

typedef __attribute__((address_space(1))) const void* as1cv;
typedef __attribute__((address_space(3))) void* as3v;

__device__ inline void gload_lds16(const void* g, void* l) {
  __builtin_amdgcn_global_load_lds((as1cv)g, (as3v)l, 16, 0, 0);
}

// ---------------- prep: VtS in STAGED order (unchanged, verified R9-R17).
// VtS[((i*16+t32)*21+q)*512 + l*8 + e] = B-panel value for row n=16q+(l>>2),
// kk = t32*32 + ((l&3)^((l>>3)&3))*8 + e.  n<320 -> v; n==320 -> w; else 0.
__global__ __launch_bounds__(256) void prep_vt(const float* __restrict__ v,
                                               const float* __restrict__ w,
                                               __bf16* __restrict__ VtS) {
  const int i = blockIdx.x / NFRG;
  const int q = blockIdx.x % NFRG;
  const int tdx = threadIdx.x;
  __shared__ float lv[FS * 17];
  if (q < NF) {  // panel for g=q: lv[s*17+k] = v[g, i*500+s, k]
    const int k = tdx & 15, sb = tdx >> 4;
    const float* vb = v + ((size_t)q * TFEAT + (size_t)i * FS) * KD;
    for (int it = 0; it < 32; ++it) {
      int s = it * 16 + sb;
      if (s < FS) lv[s * 17 + k] = vb[(size_t)s * KD + k];
    }
    __syncthreads();
  }
  const float* wf = w + (size_t)i * FS;
  __bf16* base = VtS + ((size_t)i * 16 * NFRG + q) * 512;
  for (int it = 0; it < 4; ++it) {
    int p = it * 256 + tdx;            // (t32,l) pair: 16*64 = 1024
    int t = p >> 6, l = p & 63;
    int r = l >> 2;                    // row within group (= k for q<20)
    int kk = t * 32 + (((l & 3) ^ ((l >> 3) & 3)) << 3);
    bf16x8 h;
#pragma unroll
    for (int e = 0; e < 8; ++e) {
      int s = kk + e;
      float val = 0.f;
      if (s < FS) {
        if (q < NF) val = lv[s * 17 + r];
        else if (r == 0) val = wf[s];
      }
      h[e] = (__bf16)val;
    }
    *(bf16x8*)(base + (size_t)t * (NFRG * 512) + l * 8) = h;
  }
}

typedef __bf16 AsT[64][32];
typedef __bf16 BsT[NCOL * 32];

// ---------------- K1: per-field GEMM (R12 body, verified best) + fused finisher.
// BM=64, BN=336, BK=64, 8 K-steps, 4 waves. LDS 51.2 KB -> 3 blocks/CU.
// Finisher (last of 20 field blocks per tile): per wave, per row, stage the
// 20x320 interaction block into the wave's 12.8 KB LDS segment with coalesced
// u32x4 loads (k2's proven pattern), then LDS compute.
__global__ __launch_bounds__(256, 3) void k1_gemm(
    const float* __restrict__ x, const __bf16* __restrict__ VtS,
    __bf16* __restrict__ E2, float* __restrict__ out, int* __restrict__ cnt,
    int chunk_base, int tiles) {
  __shared__ __align__(16) char smem[51200];   // As[2][64][32] + Bs[2][NCOL*32]
  __shared__ int lastFlag;
  AsT* As = (AsT*)smem;                        // 8192 B
  BsT* Bs = (BsT*)(smem + 8192);               // 43008 B

  int bid = blockIdx.x;
  const int nwg = gridDim.x;
  if ((nwg & 7) == 0) {                   // bijective XCD swizzle
    int cpx = nwg >> 3;
    bid = (bid & 7) * cpx + (bid >> 3);
  }
  const int i  = bid / tiles;
  const int tb = bid % tiles;
  const int tid = threadIdx.x;
  const int lane = tid & 63, wid = tid >> 6;
  const int b0 = chunk_base + tb * 64;

  // A stage (per thread): row = tid>>2, 16 f32 cols at (tid&3)*16 within 64-step
  const int arow = tid >> 2;
  const int ac16 = (tid & 3) * 16;
  const int ah  = (tid & 3) >> 1;                  // k-half this thread writes
  const int gh0 = (2 * (tid & 3)) & 3;             // granule-in-half (0 or 2)
  const int rsw = (arow >> 1) & 3;                 // row swizzle
  const float* xrow = x + (size_t)(b0 + arow) * TFEAT + i * FS;
  const __bf16* VtSi = VtS + (size_t)i * 16 * NFRG * 512 + lane * 8;

  auto issueB = [&](int t) {   // stage substeps 2t,2t+1 into halves 0,1
#pragma unroll
    for (int jj = 0; jj < 6; ++jj) {
      int q = wid + 4 * jj;
      if (q < NFRG) {
        gload_lds16(VtSi + ((size_t)(2 * t) * NFRG + q) * 512,
                    (void*)&Bs[0][q * 512]);
        gload_lds16(VtSi + ((size_t)(2 * t + 1) * NFRG + q) * 512,
                    (void*)&Bs[1][q * 512]);
      }
    }
  };

  f32x4 ar_[4];
  auto aload = [&](int t) {
#pragma unroll
    for (int j = 0; j < 4; ++j) {
      int c = t * 64 + ac16 + j * 4;
      if (c > 496) c = 496;              // clamp: junk cols pair with zero B rows
      ar_[j] = *(const f32x4*)(xrow + c);
    }
  };
  auto astore = [&]() {
    bf16x8 h0, h1;
#pragma unroll
    for (int e = 0; e < 4; ++e) {
      h0[e] = (__bf16)ar_[0][e]; h0[4 + e] = (__bf16)ar_[1][e];
      h1[e] = (__bf16)ar_[2][e]; h1[4 + e] = (__bf16)ar_[3][e];
    }
    *(bf16x8*)(&As[ah][arow][((gh0)     ^ rsw) * 8]) = h0;
    *(bf16x8*)(&As[ah][arow][((gh0 + 1) ^ rsw) * 8]) = h1;
  };

  const int nfr = wid ? 5 : 6;
  const int Fbase = wid ? (1 + wid * 5) : 0;
  const int ar = lane & 15, akc = lane >> 4;

  f32x4 acc[4][6];
#pragma unroll
  for (int m = 0; m < 4; ++m)
#pragma unroll
    for (int nf = 0; nf < 6; ++nf) acc[m][nf] = (f32x4){0.f, 0.f, 0.f, 0.f};

  // prologue: tile 0 fully staged
  aload(0);
  issueB(0);
  astore();
  asm volatile("s_waitcnt vmcnt(0) lgkmcnt(0)" ::: "memory");
  __builtin_amdgcn_s_barrier();

  for (int t = 0; t < 8; ++t) {
    if (t < 7) aload(t + 1);             // 4 dwordx4, age under compute
    __builtin_amdgcn_sched_barrier(0);

#pragma unroll
    for (int ks = 0; ks < 2; ++ks) {
      bf16x8 af[4];
#pragma unroll
      for (int m = 0; m < 4; ++m) {
        int row = m * 16 + ar;
        int pch = akc ^ ((row >> 1) & 3);
        af[m] = *(const bf16x8*)(&As[ks][row][pch * 8]);
      }
#pragma unroll
      for (int nf = 0; nf < 6; ++nf)
        if (nf < nfr) {
          int n_ = (Fbase + nf) * 16 + ar;
          int pc = akc ^ ((n_ >> 1) & 3);
          bf16x8 bfr = *(const bf16x8*)&Bs[ks][n_ * 32 + pc * 8];
#pragma unroll
          for (int m = 0; m < 4; ++m)
            acc[m][nf] = __builtin_amdgcn_mfma_f32_16x16x32_bf16(af[m], bfr,
                                                                 acc[m][nf], 0, 0, 0);
        }
    }
    if (t < 7) {
      __builtin_amdgcn_s_barrier();      // all waves done reading LDS tile t
      issueB(t + 1);                     // 12 glds (issued first)
      astore();                          // ds_write; reg-wait leaves glds in flight
      asm volatile("s_waitcnt vmcnt(0) lgkmcnt(0)" ::: "memory");
      __builtin_amdgcn_s_barrier();      // tile t+1 ready
    }
  }

  // epilogue: C/D layout col=lane&15, row=(lane>>4)*4+r
  const int lr4 = akc * 4, lcol = lane & 15;
#pragma unroll
  for (int m = 0; m < 4; ++m)
#pragma unroll
    for (int nf = 0; nf < 6; ++nf)
      if (nf < nfr) {
        int n = (Fbase + nf) * 16 + lcol;
#pragma unroll
        for (int r = 0; r < 4; ++r) {
          int bl = tb * 64 + m * 16 + lr4 + r;
          E2[(size_t)bl * ROWE + i * NCOL + n] = (__bf16)acc[m][nf][r];
        }
      }

  // ---- fused finisher: last of the 20 field-blocks for this batch-tile
  const int tileId = (chunk_base >> 6) + tb;
  __syncthreads();                       // E2 stores drained; LDS free for reuse
  if (tid == 0) {
    __threadfence();                     // device-scope release
    int prev = atomicAdd(cnt + tileId, 1);
    lastFlag = (prev == NF - 1) ? 1 : 0;
    if (lastFlag) __threadfence();       // acquire
  }
  __syncthreads();
  if (!lastFlag) return;

  // per wave: 16 rows; stage 20x320 interaction block (12.8 KB) coalesced,
  // then k2's LDS compute (stride 320). Wave-private segment -> no barrier.
  u32x4* dstv = (u32x4*)(smem + (size_t)wid * 12800);
  const __bf16* shv = (const __bf16*)(smem + (size_t)wid * 12800);
  const int k = lane & 15, g = lane >> 4;
  for (int rr = 0; rr < 16; ++rr) {
    const int blr = wid * 16 + rr;
    const __bf16* er = E2 + (size_t)(tb * 64 + blr) * ROWE;
    const u32x4* srcv = (const u32x4*)er;      // 16B-aligned (ROWE*2 % 16 == 0)
#pragma unroll
    for (int it = 0; it < 13; ++it) {
      int idx = it * 64 + lane;                // 16B units; 800 total
      if (idx < 800) {
        int ii = idx / 40, off = idx - ii * 40;    // row ii: 42 units, keep 40
        dstv[idx] = srcv[ii * 42 + off];
      }
    }
    float lin = (lane < NF) ? (float)er[lane * NCOL + 320] : 0.f;
    asm volatile("s_waitcnt vmcnt(0) lgkmcnt(0)" ::: "memory");
    float sum = lin;
    for (int ii = g; ii < NF; ii += 4)
      for (int j = ii + 1; j < NF; ++j)
        sum += (float)shv[ii * 320 + j * 16 + k] * (float)shv[j * 320 + ii * 16 + k];
#pragma unroll
    for (int off = 32; off; off >>= 1) sum += __shfl_xor(sum, off);
    if (lane == 0) out[b0 + blr] = sum;
  }
}

extern "C" void kernel_launch(void* const* d_in, const int* in_sizes, int n_in,
                              void* d_out, int out_size, void* d_ws, size_t ws_size,
                              hipStream_t stream) {
  const float* x = (const float*)d_in[0];
  const float* w = (const float*)d_in[1];
  const float* v = (const float*)d_in[2];
  float* out = (float*)d_out;
  char* ws = (char*)d_ws;

  const size_t vt_bytes = (size_t)NF * 16 * NFRG * 512 * 2;   // 6,881,280
  __bf16* VtS = (__bf16*)ws;
  int* cnt = (int*)(ws + vt_bytes);                           // 64 tile counters
  __bf16* E2 = (__bf16*)(ws + vt_bytes + 256);

  size_t eavail = (ws_size > vt_bytes + 256) ? ws_size - vt_bytes - 256 : 0;
  int Bc = NB;
  while (Bc > 64 && (size_t)Bc * ROWE * 2 > eavail) Bc >>= 1;

  hipMemsetAsync(cnt, 0, (NB / 64) * sizeof(int), stream);
  prep_vt<<<NF * NFRG, 256, 0, stream>>>(v, w, VtS);
  for (int cb = 0; cb < NB; cb += Bc) {
    int tiles = Bc / 64;
    k1_gemm<<<NF * tiles, 256, 0, stream>>>(x, VtS, E2, out, cnt, cb, tiles);
  }
}

// Round 19
// 72.916 us; speedup vs baseline: 4.9061x; 2.7008x over previous
//
#include <hip/hip_runtime.h>
#include <stdint.h>

// FFM: B=4096, F=20 fields x S=500 feats, K=16.
// E2[b, i*336 + g*16 + k] = sum_s x[b,i*500+s]*v[g,i*500+s,k]  (g<20)
// E2[b, i*336 + 320]      = sum_s x[b,i*500+s]*w[i*500+s]      (linear partial)
// out[b] = sum_i E2[b,i,320] + sum_{i<j,k} E2[b,i*336+j*16+k]*E2[b,j*336+i*16+k]
// R19 = R12 verbatim (best verified: 72.6 us). Fusion (R17/18) and all deeper
// pipeline variants (R13-R16) regressed; this is the empirical optimum.

#define NF 20
#define FS 500
#define TFEAT 10000
#define KD 16
#define NCOL 336        // 21 frags: 320 interaction cols + 16-col w block
#define NFRG 21
#define NB 4096
#define ROWE (NF * NCOL)  // 6720

typedef __bf16 bf16x8 __attribute__((ext_vector_type(8)));
typedef __bf16 bf16x2 __attribute__((ext_vector_type(2)));
typedef float  f32x4  __attribute__((ext_vector_type(4)));
typedef unsigned int u32x4 __attribute__((ext_vector_type(4)));

typedef __attribute__((address_space(1))) const void* as1cv;
typedef __attribute__((address_space(3))) void* as3v;

__device__ inline void gload_lds16(const void* g, void* l) {
  __builtin_amdgcn_global_load_lds((as1cv)g, (as3v)l, 16, 0, 0);
}

// ---------------- prep: VtS in STAGED order (verified R9-R18).
// VtS[((i*16+t32)*21+q)*512 + l*8 + e] = B-panel value for row n=16q+(l>>2),
// kk = t32*32 + ((l&3)^((l>>3)&3))*8 + e.  n<320 -> v; n==320 -> w; else 0.
__global__ __launch_bounds__(256) void prep_vt(const float* __restrict__ v,
                                               const float* __restrict__ w,
                                               __bf16* __restrict__ VtS) {
  const int i = blockIdx.x / NFRG;
  const int q = blockIdx.x % NFRG;
  const int tdx = threadIdx.x;
  __shared__ float lv[FS * 17];
  if (q < NF) {  // panel for g=q: lv[s*17+k] = v[g, i*500+s, k]
    const int k = tdx & 15, sb = tdx >> 4;
    const float* vb = v + ((size_t)q * TFEAT + (size_t)i * FS) * KD;
    for (int it = 0; it < 32; ++it) {
      int s = it * 16 + sb;
      if (s < FS) lv[s * 17 + k] = vb[(size_t)s * KD + k];
    }
    __syncthreads();
  }
  const float* wf = w + (size_t)i * FS;
  __bf16* base = VtS + ((size_t)i * 16 * NFRG + q) * 512;
  for (int it = 0; it < 4; ++it) {
    int p = it * 256 + tdx;            // (t32,l) pair: 16*64 = 1024
    int t = p >> 6, l = p & 63;
    int r = l >> 2;                    // row within group (= k for q<20)
    int kk = t * 32 + (((l & 3) ^ ((l >> 3) & 3)) << 3);
    bf16x8 h;
#pragma unroll
    for (int e = 0; e < 8; ++e) {
      int s = kk + e;
      float val = 0.f;
      if (s < FS) {
        if (q < NF) val = lv[s * 17 + r];
        else if (r == 0) val = wf[s];
      }
      h[e] = (__bf16)val;
    }
    *(bf16x8*)(base + (size_t)t * (NFRG * 512) + l * 8) = h;
  }
}

// ---------------- K1: per-field GEMM. BM=64, BN=336, BK=64, 8 K-steps, 4 waves.
// Single-buffered m97-style 2-barrier loop; the two 32-wide k-halves use the
// verified 0-conflict XOR sub-layouts. A reg-staged distance-1; stage region:
// glds first, astore reg-wait leaves glds in flight, then vmcnt(0)+barrier.
// LDS 51.2 KB -> 3 blocks/CU. XCD-bijective swizzle.
__global__ __launch_bounds__(256, 3) void k1_gemm(
    const float* __restrict__ x, const __bf16* __restrict__ VtS,
    __bf16* __restrict__ E2, int chunk_base, int tiles) {
  __shared__ __bf16 As[2][64][32];        // k-halves, 8192 B
  __shared__ __bf16 Bs[2][NCOL * 32];     // k-halves, 43008 B

  int bid = blockIdx.x;
  const int nwg = gridDim.x;
  if ((nwg & 7) == 0) {                   // bijective XCD swizzle
    int cpx = nwg >> 3;
    bid = (bid & 7) * cpx + (bid >> 3);
  }
  const int i  = bid / tiles;
  const int tb = bid % tiles;
  const int tid = threadIdx.x;
  const int lane = tid & 63, wid = tid >> 6;
  const int b0 = chunk_base + tb * 64;

  // A stage (per thread): row = tid>>2, 16 f32 cols at (tid&3)*16 within 64-step
  const int arow = tid >> 2;
  const int ac16 = (tid & 3) * 16;
  const int ah  = (tid & 3) >> 1;                  // k-half this thread writes
  const int gh0 = (2 * (tid & 3)) & 3;             // granule-in-half (0 or 2)
  const int rsw = (arow >> 1) & 3;                 // row swizzle
  const float* xrow = x + (size_t)(b0 + arow) * TFEAT + i * FS;
  const __bf16* VtSi = VtS + (size_t)i * 16 * NFRG * 512 + lane * 8;

  auto issueB = [&](int t) {   // stage substeps 2t,2t+1 into halves 0,1
#pragma unroll
    for (int jj = 0; jj < 6; ++jj) {
      int q = wid + 4 * jj;
      if (q < NFRG) {
        gload_lds16(VtSi + ((size_t)(2 * t) * NFRG + q) * 512,
                    (void*)&Bs[0][q * 512]);
        gload_lds16(VtSi + ((size_t)(2 * t + 1) * NFRG + q) * 512,
                    (void*)&Bs[1][q * 512]);
      }
    }
  };

  f32x4 ar_[4];
  auto aload = [&](int t) {
#pragma unroll
    for (int j = 0; j < 4; ++j) {
      int c = t * 64 + ac16 + j * 4;
      if (c > 496) c = 496;              // clamp: junk cols pair with zero B rows
      ar_[j] = *(const f32x4*)(xrow + c);
    }
  };
  auto astore = [&]() {
    bf16x8 h0, h1;
#pragma unroll
    for (int e = 0; e < 4; ++e) {
      h0[e] = (__bf16)ar_[0][e]; h0[4 + e] = (__bf16)ar_[1][e];
      h1[e] = (__bf16)ar_[2][e]; h1[4 + e] = (__bf16)ar_[3][e];
    }
    *(bf16x8*)(&As[ah][arow][((gh0)     ^ rsw) * 8]) = h0;
    *(bf16x8*)(&As[ah][arow][((gh0 + 1) ^ rsw) * 8]) = h1;
  };

  const int nfr = wid ? 5 : 6;
  const int Fbase = wid ? (1 + wid * 5) : 0;
  const int ar = lane & 15, akc = lane >> 4;

  f32x4 acc[4][6];
#pragma unroll
  for (int m = 0; m < 4; ++m)
#pragma unroll
    for (int nf = 0; nf < 6; ++nf) acc[m][nf] = (f32x4){0.f, 0.f, 0.f, 0.f};

  // prologue: tile 0 fully staged
  aload(0);
  issueB(0);
  astore();
  asm volatile("s_waitcnt vmcnt(0) lgkmcnt(0)" ::: "memory");
  __builtin_amdgcn_s_barrier();

  for (int t = 0; t < 8; ++t) {
    if (t < 7) aload(t + 1);             // 4 dwordx4, age under compute
    __builtin_amdgcn_sched_barrier(0);

#pragma unroll
    for (int ks = 0; ks < 2; ++ks) {
      bf16x8 af[4];
#pragma unroll
      for (int m = 0; m < 4; ++m) {
        int row = m * 16 + ar;
        int pch = akc ^ ((row >> 1) & 3);
        af[m] = *(const bf16x8*)(&As[ks][row][pch * 8]);
      }
#pragma unroll
      for (int nf = 0; nf < 6; ++nf)
        if (nf < nfr) {
          int n_ = (Fbase + nf) * 16 + ar;
          int pc = akc ^ ((n_ >> 1) & 3);
          bf16x8 bfr = *(const bf16x8*)&Bs[ks][n_ * 32 + pc * 8];
#pragma unroll
          for (int m = 0; m < 4; ++m)
            acc[m][nf] = __builtin_amdgcn_mfma_f32_16x16x32_bf16(af[m], bfr,
                                                                 acc[m][nf], 0, 0, 0);
        }
    }
    if (t < 7) {
      __builtin_amdgcn_s_barrier();      // all waves done reading LDS tile t
      issueB(t + 1);                     // 12 glds (issued first)
      astore();                          // ds_write; reg-wait leaves glds in flight
      asm volatile("s_waitcnt vmcnt(0) lgkmcnt(0)" ::: "memory");
      __builtin_amdgcn_s_barrier();      // tile t+1 ready
    }
  }

  // epilogue: C/D layout col=lane&15, row=(lane>>4)*4+r
  const int lr4 = akc * 4, lcol = lane & 15;
#pragma unroll
  for (int m = 0; m < 4; ++m)
#pragma unroll
    for (int nf = 0; nf < 6; ++nf)
      if (nf < nfr) {
        int n = (Fbase + nf) * 16 + lcol;
#pragma unroll
        for (int r = 0; r < 4; ++r) {
          int bl = tb * 64 + m * 16 + lr4 + r;
          E2[(size_t)bl * ROWE + i * NCOL + n] = (__bf16)acc[m][nf][r];
        }
      }
}

// ---------------- K2: pair + linear reduction, 1 wave per batch row
__global__ __launch_bounds__(256) void k2_pair(
    const __bf16* __restrict__ E2, float* __restrict__ out, int chunk_base) {
  __shared__ __align__(16) unsigned shw[4][3360];  // 13440 B per wave
  const int tid = threadIdx.x, lane = tid & 63, wid = tid >> 6;
  const int bl = blockIdx.x * 4 + wid;
  const unsigned* src = (const unsigned*)(E2 + (size_t)bl * ROWE);
  for (int it = 0; it < 14; ++it) {
    int idx = it * 64 + lane;             // 16B units; 840 total
    if (idx < 840) {
      u32x4 val = *(const u32x4*)(src + (size_t)idx * 4);
      *(u32x4*)&shw[wid][idx * 4] = val;
    }
  }
  __syncthreads();
  const __bf16* sh = (const __bf16*)shw[wid];
  const int k = lane & 15, g = lane >> 4;
  float sum = 0.f;
  for (int i = g; i < NF; i += 4)
    for (int j = i + 1; j < NF; ++j)
      sum += (float)sh[i * NCOL + j * 16 + k] * (float)sh[j * NCOL + i * 16 + k];
  if (lane < NF) sum += (float)sh[lane * NCOL + 320];   // linear term
#pragma unroll
  for (int off = 32; off; off >>= 1) sum += __shfl_xor(sum, off);
  if (lane == 0) out[chunk_base + bl] = sum;
}

extern "C" void kernel_launch(void* const* d_in, const int* in_sizes, int n_in,
                              void* d_out, int out_size, void* d_ws, size_t ws_size,
                              hipStream_t stream) {
  const float* x = (const float*)d_in[0];
  const float* w = (const float*)d_in[1];
  const float* v = (const float*)d_in[2];
  float* out = (float*)d_out;
  char* ws = (char*)d_ws;

  const size_t vt_bytes = (size_t)NF * 16 * NFRG * 512 * 2;   // 6,881,280
  __bf16* VtS = (__bf16*)ws;
  __bf16* E2 = (__bf16*)(ws + vt_bytes);

  size_t eavail = (ws_size > vt_bytes) ? ws_size - vt_bytes : 0;
  int Bc = NB;
  while (Bc > 64 && (size_t)Bc * ROWE * 2 > eavail) Bc >>= 1;

  prep_vt<<<NF * NFRG, 256, 0, stream>>>(v, w, VtS);
  for (int cb = 0; cb < NB; cb += Bc) {
    int tiles = Bc / 64;
    k1_gemm<<<NF * tiles, 256, 0, stream>>>(x, VtS, E2, cb, tiles);
    k2_pair<<<Bc / 4, 256, 0, stream>>>(E2, out, cb);
  }
}